// Round 9
// baseline (382.294 us; speedup 1.0000x reference)
//
#include <hip/hip_runtime.h>

// ============================================================================
// PROBE ROUND: kernels are byte-identical to round 8, but each body runs in
// an idempotent internal rep loop (proj x4, score x8, attn x16) so every
// dispatch exceeds the ~39us harness-fill threshold and lands in the top-5
// rocprof table with full counters. Per-kernel time = dur_us / REP.
// ============================================================================

// Problem constants (fixed by setup_inputs): B=4, S=256, D=512, P=256
constexpr int B = 4;
constexpr int S = 256;
constexpr int D = 512;
constexpr int P = 256;
constexpr float NEG_INF = -1e9f;
constexpr float LOG2E = 1.4426950408889634f;
constexpr float C2 = 2.885390081777927f; // 2*log2(e):  exp2(C2*x) = e^{2x}

__device__ __forceinline__ float fast_exp2(float x) {
#if __has_builtin(__builtin_amdgcn_exp2f)
    return __builtin_amdgcn_exp2f(x);
#else
    return exp2f(x);
#endif
}

__device__ __forceinline__ float fast_rcp(float x) {
#if __has_builtin(__builtin_amdgcn_rcpf)
    return __builtin_amdgcn_rcpf(x);
#else
    return 1.0f / x;
#endif
}

// ---------------------------------------------------------------------------
// proj (R8 version, REP=4): tile 16m x 64n, K-tile 64, 512 blocks.
// ---------------------------------------------------------------------------
__global__ __launch_bounds__(256)
void proj_kernel(const float* __restrict__ seq,
                 const float* __restrict__ W1, const float* __restrict__ W2,
                 float* __restrict__ Eq, float* __restrict__ EkT) {
    __shared__ float As[64][17]; // [k][m]
    __shared__ float Ws[64][68]; // [k][n]

    int bid0 = blockIdx.x;
    int bid = (bid0 & 7) * 64 + (bid0 >> 3); // XCD swizzle (512 = 8*64)

    const float* A;
    const float* Bp;
    float* out;
    if (bid < 256) { // Eq
        int mt = bid >> 2, nt = bid & 3;
        A = seq + (size_t)mt * 16 * D;
        Bp = W2 + (size_t)nt * 64 * D;
        out = Eq + (size_t)mt * 16 * 256 + nt * 64;
    } else {         // EkT
        int r = bid - 256;
        int b = r >> 6, t = r & 63;
        int mt = t >> 2, nt = t & 3;
        A = W1 + (size_t)mt * 16 * D;
        Bp = seq + ((size_t)b * S + nt * 64) * D;
        out = EkT + (size_t)b * P * S + (size_t)mt * 16 * 256 + nt * 64;
    }

    int tid = threadIdx.x;
    int tx = tid & 15, ty = tid >> 4;
    int arow = tid >> 4, akc = tid & 15;
    int brow = tid >> 2, bcg = tid & 3;
    const float* aptr = A + (size_t)arow * D + akc * 4;
    const float* bptr = Bp + (size_t)brow * D + bcg * 16;

    for (int rep = 0; rep < 4; ++rep) {
        __syncthreads();
        float4 a0, w0, w1, w2, w3;
        a0 = *(const float4*)(aptr);
        w0 = *(const float4*)(bptr);      w1 = *(const float4*)(bptr + 4);
        w2 = *(const float4*)(bptr + 8);  w3 = *(const float4*)(bptr + 12);

        float c0[4] = {0.f, 0.f, 0.f, 0.f};

        for (int kt = 0; kt < 8; kt++) {
            int ka = akc * 4;
            As[ka + 0][arow] = a0.x; As[ka + 1][arow] = a0.y;
            As[ka + 2][arow] = a0.z; As[ka + 3][arow] = a0.w;
            int kb = bcg * 16;
            Ws[kb + 0][brow] = w0.x;  Ws[kb + 1][brow] = w0.y;
            Ws[kb + 2][brow] = w0.z;  Ws[kb + 3][brow] = w0.w;
            Ws[kb + 4][brow] = w1.x;  Ws[kb + 5][brow] = w1.y;
            Ws[kb + 6][brow] = w1.z;  Ws[kb + 7][brow] = w1.w;
            Ws[kb + 8][brow] = w2.x;  Ws[kb + 9][brow] = w2.y;
            Ws[kb + 10][brow] = w2.z; Ws[kb + 11][brow] = w2.w;
            Ws[kb + 12][brow] = w3.x; Ws[kb + 13][brow] = w3.y;
            Ws[kb + 14][brow] = w3.z; Ws[kb + 15][brow] = w3.w;
            __syncthreads();
            if (kt < 7) {
                const float* ap = aptr + (kt + 1) * 64;
                const float* bp = bptr + (kt + 1) * 64;
                a0 = *(const float4*)(ap);
                w0 = *(const float4*)(bp);     w1 = *(const float4*)(bp + 4);
                w2 = *(const float4*)(bp + 8); w3 = *(const float4*)(bp + 12);
            }
#pragma unroll 8
            for (int k = 0; k < 64; k++) {
                float av = As[k][ty];
                float4 wv = *(const float4*)&Ws[k][tx * 4];
                c0[0] = fmaf(av, wv.x, c0[0]);
                c0[1] = fmaf(av, wv.y, c0[1]);
                c0[2] = fmaf(av, wv.z, c0[2]);
                c0[3] = fmaf(av, wv.w, c0[3]);
            }
            __syncthreads();
        }
        float4 o0 = {fast_exp2(c0[0] * C2), fast_exp2(c0[1] * C2),
                     fast_exp2(c0[2] * C2), fast_exp2(c0[3] * C2)};
        *(float4*)&out[(size_t)ty * 256 + tx * 4] = o0;
    }
}

// ---------------------------------------------------------------------------
// score v8 (R8 version, REP=8): barrier-free phase 1, direct global Ek loads.
// ---------------------------------------------------------------------------
__global__ __launch_bounds__(256)
void score_kernel(const float* __restrict__ EkT, const float* __restrict__ Eq,
                  const float* __restrict__ v, const float* __restrict__ mask,
                  float* __restrict__ wout) {
    __shared__ float Eqs[4][P];       // 4 KB
    __shared__ float vsm[P];          // 1 KB  (-2*v)
    __shared__ float part[4][4][S];   // 16 KB [w][q][j]
    __shared__ float redm[4][4], reds[4][4];

    int bid0 = blockIdx.x;
    int bid = (bid0 & 7) * 32 + (bid0 >> 3); // XCD swizzle
    int b = bid >> 6;
    int i0 = (bid & 63) * 4;
    int tid = threadIdx.x;
    int w = tid >> 6, l = tid & 63;

    // stage Eq rows (4 x 256 contiguous) and v' = -2v  (once)
    {
        const float2* src = (const float2*)(Eq + ((size_t)b * S + i0) * P);
        ((float2*)Eqs)[tid] = src[tid];
        ((float2*)Eqs)[tid + 256] = src[tid + 256];
        if (tid < 128) {
            float2 vv = ((const float2*)v)[tid];
            ((float2*)vsm)[tid] = make_float2(-2.f * vv.x, -2.f * vv.y);
        }
    }
    __syncthreads();

    for (int rep = 0; rep < 8; ++rep) {
        __syncthreads();
        // phase 1: no barriers, direct global Ek loads
        {
            int p0 = w * 64;
            const float* ekp = EkT + (size_t)b * P * S + (size_t)p0 * S + l * 4;
            float4 a0 = {0.f, 0.f, 0.f, 0.f};
            float4 a1 = a0, a2 = a0, a3 = a0;
#pragma unroll 8
            for (int pp = 0; pp < 64; ++pp) {
                float4 ek = *(const float4*)(ekp + (size_t)pp * S);
                int p = p0 + pp;
                float vv = vsm[p];
                float q0 = Eqs[0][p], q1 = Eqs[1][p];
                float q2 = Eqs[2][p], q3 = Eqs[3][p];
                a0.x = fmaf(vv, fast_rcp(fmaf(ek.x, q0, 1.f)), a0.x);
                a0.y = fmaf(vv, fast_rcp(fmaf(ek.y, q0, 1.f)), a0.y);
                a0.z = fmaf(vv, fast_rcp(fmaf(ek.z, q0, 1.f)), a0.z);
                a0.w = fmaf(vv, fast_rcp(fmaf(ek.w, q0, 1.f)), a0.w);
                a1.x = fmaf(vv, fast_rcp(fmaf(ek.x, q1, 1.f)), a1.x);
                a1.y = fmaf(vv, fast_rcp(fmaf(ek.y, q1, 1.f)), a1.y);
                a1.z = fmaf(vv, fast_rcp(fmaf(ek.z, q1, 1.f)), a1.z);
                a1.w = fmaf(vv, fast_rcp(fmaf(ek.w, q1, 1.f)), a1.w);
                a2.x = fmaf(vv, fast_rcp(fmaf(ek.x, q2, 1.f)), a2.x);
                a2.y = fmaf(vv, fast_rcp(fmaf(ek.y, q2, 1.f)), a2.y);
                a2.z = fmaf(vv, fast_rcp(fmaf(ek.z, q2, 1.f)), a2.z);
                a2.w = fmaf(vv, fast_rcp(fmaf(ek.w, q2, 1.f)), a2.w);
                a3.x = fmaf(vv, fast_rcp(fmaf(ek.x, q3, 1.f)), a3.x);
                a3.y = fmaf(vv, fast_rcp(fmaf(ek.y, q3, 1.f)), a3.y);
                a3.z = fmaf(vv, fast_rcp(fmaf(ek.z, q3, 1.f)), a3.z);
                a3.w = fmaf(vv, fast_rcp(fmaf(ek.w, q3, 1.f)), a3.w);
            }
            *(float4*)&part[w][0][l * 4] = a0;
            *(float4*)&part[w][1][l * 4] = a1;
            *(float4*)&part[w][2][l * 4] = a2;
            *(float4*)&part[w][3][l * 4] = a3;
        }
        __syncthreads();

        // phase 2: softmax over keys (all 256 threads, thread = j)
        int j = tid;
        int lane = tid & 63, wid = tid >> 6;
        float km = mask[(size_t)b * S + j];
        float s[4], e[4];
#pragma unroll
        for (int q = 0; q < 4; q++) {
            float sv = (part[0][q][j] + part[1][q][j]) +
                       (part[2][q][j] + part[3][q][j]);
            s[q] = (km > 0.f) ? sv : NEG_INF;
            float mm = s[q];
#pragma unroll
            for (int off = 32; off >= 1; off >>= 1)
                mm = fmaxf(mm, __shfl_xor(mm, off, 64));
            if (lane == 0) redm[q][wid] = mm;
        }
        __syncthreads();
#pragma unroll
        for (int q = 0; q < 4; q++) {
            float mm = fmaxf(fmaxf(redm[q][0], redm[q][1]),
                             fmaxf(redm[q][2], redm[q][3]));
            float ee = fast_exp2((s[q] - mm) * LOG2E);
            e[q] = ee;
            float ss = ee;
#pragma unroll
            for (int off = 32; off >= 1; off >>= 1)
                ss += __shfl_xor(ss, off, 64);
            if (lane == 0) reds[q][wid] = ss;
        }
        __syncthreads();
#pragma unroll
        for (int q = 0; q < 4; q++) {
            float ssum = (reds[q][0] + reds[q][1]) + (reds[q][2] + reds[q][3]);
            float qm = mask[(size_t)b * S + i0 + q];
            float wgt = e[q] * fast_rcp(ssum) * qm;
            wout[((size_t)b * S + i0 + q) * S + j] = wgt;
        }
    }
}

// ---------------------------------------------------------------------------
// attn GEMM (R8 version, REP=16): tile 16i x 64d, K=256, 512 blocks.
// ---------------------------------------------------------------------------
__global__ __launch_bounds__(256)
void attn_kernel(const float* __restrict__ wts, const float* __restrict__ seq,
                 float* __restrict__ attn) {
    __shared__ float As[64][17]; // [k][m]  (weights, transposed)
    __shared__ float Ws[64][68]; // [k][n]  (seq rows, natural layout)

    int bid0 = blockIdx.x;
    int bid = (bid0 & 7) * 64 + (bid0 >> 3); // XCD swizzle (512 = 8*64)
    int b = bid >> 7;
    int t = bid & 127;
    int i0 = (t >> 3) * 16;
    int d0 = (t & 7) * 64;

    int tid = threadIdx.x;
    int tx = tid & 15, ty = tid >> 4;
    int arow = tid >> 4, akc = tid & 15;
    int brow = tid >> 2, bcg = tid & 3;
    const float* aptr = wts + ((size_t)b * S + i0 + arow) * S + akc * 4;
    const float* bptr = seq + ((size_t)b * S + brow) * D + d0 + bcg * 16;

    for (int rep = 0; rep < 16; ++rep) {
        __syncthreads();
        float4 a0, w0, w1, w2, w3;
        a0 = *(const float4*)(aptr);
        w0 = *(const float4*)(bptr);      w1 = *(const float4*)(bptr + 4);
        w2 = *(const float4*)(bptr + 8);  w3 = *(const float4*)(bptr + 12);

        float c0[4] = {0.f, 0.f, 0.f, 0.f};

        for (int kt = 0; kt < 4; kt++) {
            int ka = akc * 4;
            As[ka + 0][arow] = a0.x; As[ka + 1][arow] = a0.y;
            As[ka + 2][arow] = a0.z; As[ka + 3][arow] = a0.w;
            int kb = bcg * 16;
            *(float4*)&Ws[brow][kb + 0] = w0;   // brow is k here
            *(float4*)&Ws[brow][kb + 4] = w1;
            *(float4*)&Ws[brow][kb + 8] = w2;
            *(float4*)&Ws[brow][kb + 12] = w3;
            __syncthreads();
            if (kt < 3) {
                const float* ap = aptr + (kt + 1) * 64;
                const float* bp = bptr + (size_t)(kt + 1) * 64 * D;
                a0 = *(const float4*)(ap);
                w0 = *(const float4*)(bp);     w1 = *(const float4*)(bp + 4);
                w2 = *(const float4*)(bp + 8); w3 = *(const float4*)(bp + 12);
            }
#pragma unroll 8
            for (int k = 0; k < 64; k++) {
                float av = As[k][ty];
                float4 wv = *(const float4*)&Ws[k][tx * 4];
                c0[0] = fmaf(av, wv.x, c0[0]);
                c0[1] = fmaf(av, wv.y, c0[1]);
                c0[2] = fmaf(av, wv.z, c0[2]);
                c0[3] = fmaf(av, wv.w, c0[3]);
            }
            __syncthreads();
        }
        *(float4*)&attn[((size_t)b * S + i0 + ty) * D + d0 + tx * 4] =
            make_float4(c0[0], c0[1], c0[2], c0[3]);
    }
}

// ---------------------------------------------------------------------------
extern "C" void kernel_launch(void* const* d_in, const int* in_sizes, int n_in,
                              void* d_out, int out_size, void* d_ws, size_t ws_size,
                              hipStream_t stream) {
    const float* seq  = (const float*)d_in[0];
    const float* mask = (const float*)d_in[1];
    const float* W1   = (const float*)d_in[2];
    const float* W2   = (const float*)d_in[3];
    const float* v    = (const float*)d_in[4];

    float* attn = (float*)d_out;                 // [B,S,D]
    float* wout = attn + (size_t)B * S * D;      // [B,S,S]

    float* Eq  = (float*)d_ws;                   // [B*S, P]  = exp2(C2*pq)
    float* EkT = Eq + (size_t)B * S * P;         // [B, P, S] = exp2(C2*pk)^T

    proj_kernel<<<512, 256, 0, stream>>>(seq, W1, W2, Eq, EkT);
    score_kernel<<<B * (S / 4), 256, 0, stream>>>(EkT, Eq, v, mask, wout);
    attn_kernel<<<512, 256, 0, stream>>>(wout, seq, attn);
}

// Round 10
// 58.913 us; speedup vs baseline: 6.4891x; 6.4891x over previous
//
#include <hip/hip_runtime.h>

// Problem constants (fixed by setup_inputs): B=4, S=256, D=512, P=256
constexpr int B = 4;
constexpr int S = 256;
constexpr int D = 512;
constexpr int P = 256;
constexpr float NEG_INF = -1e9f;
constexpr float LOG2E = 1.4426950408889634f;
constexpr float C2 = 2.885390081777927f; // 2*log2(e): exp2(C2*x) = e^{2x}

__device__ __forceinline__ float fast_exp2(float x) {
#if __has_builtin(__builtin_amdgcn_exp2f)
    return __builtin_amdgcn_exp2f(x);
#else
    return exp2f(x);
#endif
}

__device__ __forceinline__ float fast_rcp(float x) {
#if __has_builtin(__builtin_amdgcn_rcpf)
    return __builtin_amdgcn_rcpf(x);
#else
    return 1.0f / x;
#endif
}

// ---------------------------------------------------------------------------
// K0: seqT[d][m] = seq[m][d]  (1024x512 -> 512x1024). 128 blocks, 256 thr.
// seqT lives in the attn region of d_out (consumed by proj, then overwritten).
// ---------------------------------------------------------------------------
__global__ __launch_bounds__(256)
void transpose_kernel(const float* __restrict__ seq, float* __restrict__ seqT) {
    __shared__ float t[64][68];
    int b0 = blockIdx.x;
    int bid = (b0 & 7) * 16 + (b0 >> 3); // XCD swizzle (128 = 8*16)
    int mt = bid >> 3, dt = bid & 7;
    int m0 = mt * 64, d0 = dt * 64;
    int tid = threadIdx.x;
    int r = tid >> 4, c = (tid & 15) * 4;
#pragma unroll
    for (int rr = 0; rr < 4; rr++) {
        int row = r + rr * 16;
        *(float4*)&t[row][c] =
            *(const float4*)(seq + (size_t)(m0 + row) * D + d0 + c);
    }
    __syncthreads();
#pragma unroll
    for (int rr = 0; rr < 4; rr++) {
        int drow = r + rr * 16;
        float4 o;
        o.x = t[c + 0][drow];
        o.y = t[c + 1][drow];
        o.z = t[c + 2][drow];
        o.w = t[c + 3][drow];
        *(float4*)(seqT + (size_t)(d0 + drow) * 1024 + m0 + c) = o;
    }
}

// ---------------------------------------------------------------------------
// K1: broadcast-GEMM proj.  out[p][m] = exp2(C2 * W[p]·seqT[:,m])
//   bid < 256 : EqT (W = W2) ; bid >= 256 : EkT (W = W1)
// Block: 64 m (lanes) x 16 p (4 waves x 4 p). W-tile 16x512 staged once in
// LDS (one barrier); k-loop: 4 coalesced seqT loads + 4 b128 broadcasts +
// 16 fma per lane. No k-loop LDS data-path cost, no k-loop barriers.
// 512 blocks (2/CU), 256 threads.
// ---------------------------------------------------------------------------
__global__ __launch_bounds__(256)
void proj_kernel(const float* __restrict__ seqT,
                 const float* __restrict__ W1, const float* __restrict__ W2,
                 float* __restrict__ EqT, float* __restrict__ EkT) {
    __shared__ float Ws[16][520]; // [p][k] natural, padded row (16B aligned)

    int b0 = blockIdx.x;
    int bid = (b0 & 7) * 64 + (b0 >> 3); // XCD swizzle (512 = 8*64)
    const float* W;
    float* out;
    int r;
    if (bid < 256) { r = bid;       W = W2; out = EqT; }
    else           { r = bid - 256; W = W1; out = EkT; }
    int m0 = (r & 15) * 64;
    int p0 = (r >> 4) * 16;
    int tid = threadIdx.x;

    // stage W tile [16][512], coalesced reads, once
    {
        int nr = tid >> 4, cg = (tid & 15) * 4;
        const float* wr = W + (size_t)(p0 + nr) * D + cg;
#pragma unroll
        for (int t8 = 0; t8 < 8; t8++)
            *(float4*)&Ws[nr][cg + t8 * 64] = *(const float4*)(wr + t8 * 64);
    }
    __syncthreads();

    int w = tid >> 6, l = tid & 63;
    int n0 = w * 4;
    const float* ap = seqT + m0 + l;
    float acc0 = 0.f, acc1 = 0.f, acc2 = 0.f, acc3 = 0.f;
#pragma unroll 4
    for (int k4 = 0; k4 < 128; k4++) {
        float a0 = ap[(size_t)(4 * k4 + 0) * 1024];
        float a1 = ap[(size_t)(4 * k4 + 1) * 1024];
        float a2 = ap[(size_t)(4 * k4 + 2) * 1024];
        float a3 = ap[(size_t)(4 * k4 + 3) * 1024];
        float4 w0 = *(const float4*)&Ws[n0 + 0][4 * k4];
        float4 w1 = *(const float4*)&Ws[n0 + 1][4 * k4];
        float4 w2 = *(const float4*)&Ws[n0 + 2][4 * k4];
        float4 w3 = *(const float4*)&Ws[n0 + 3][4 * k4];
        acc0 = fmaf(a0, w0.x, acc0); acc0 = fmaf(a1, w0.y, acc0);
        acc0 = fmaf(a2, w0.z, acc0); acc0 = fmaf(a3, w0.w, acc0);
        acc1 = fmaf(a0, w1.x, acc1); acc1 = fmaf(a1, w1.y, acc1);
        acc1 = fmaf(a2, w1.z, acc1); acc1 = fmaf(a3, w1.w, acc1);
        acc2 = fmaf(a0, w2.x, acc2); acc2 = fmaf(a1, w2.y, acc2);
        acc2 = fmaf(a2, w2.z, acc2); acc2 = fmaf(a3, w2.w, acc2);
        acc3 = fmaf(a0, w3.x, acc3); acc3 = fmaf(a1, w3.y, acc3);
        acc3 = fmaf(a2, w3.z, acc3); acc3 = fmaf(a3, w3.w, acc3);
    }
    out[(size_t)(p0 + n0 + 0) * 1024 + m0 + l] = fast_exp2(acc0 * C2);
    out[(size_t)(p0 + n0 + 1) * 1024 + m0 + l] = fast_exp2(acc1 * C2);
    out[(size_t)(p0 + n0 + 2) * 1024 + m0 + l] = fast_exp2(acc2 * C2);
    out[(size_t)(p0 + n0 + 3) * 1024 + m0 + l] = fast_exp2(acc3 * C2);
}

// ---------------------------------------------------------------------------
// K2: score. block = (b, 4 queries), 512 threads, 256 blocks (2 waves/SIMD).
//  score(i,j) = const + sum_p (-2 v[p]) * rcp(Eq[i,p]*Ek[p,j] + 1)
// Phase 1: wave w owns p in [32w, 32w+32); lane l owns j-quad 4l..4l+3;
// coalesced EkT float4 loads, Eq/v broadcasts, no barriers.
// Phase 2: softmax (threads 0..255 = key j) -> wout (query-mask applied).
// ---------------------------------------------------------------------------
__global__ __launch_bounds__(512)
void score_kernel(const float* __restrict__ EkT, const float* __restrict__ EqT,
                  const float* __restrict__ v, const float* __restrict__ mask,
                  float* __restrict__ wout) {
    __shared__ float Eqs[4][P];       // 4 KB
    __shared__ float vsm[P];          // 1 KB (-2v)
    __shared__ float part[8][4][S];   // 32 KB [w][q][j]
    __shared__ float redm[4][4], reds[4][4];

    int b0 = blockIdx.x;
    int bid = (b0 & 7) * 32 + (b0 >> 3); // XCD swizzle (256 = 8*32)
    int b = bid >> 6;
    int i0 = (bid & 63) * 4;
    int i0g = b * S + i0;
    int tid = threadIdx.x;

    if (tid < 256) { // gather 4 EqT columns (once per block)
        float4 eq4 = *(const float4*)(EqT + (size_t)tid * 1024 + i0g);
        Eqs[0][tid] = eq4.x; Eqs[1][tid] = eq4.y;
        Eqs[2][tid] = eq4.z; Eqs[3][tid] = eq4.w;
    } else if (tid < 384) {
        int x = tid - 256;
        float2 vv = ((const float2*)v)[x];
        ((float2*)vsm)[x] = make_float2(-2.f * vv.x, -2.f * vv.y);
    }
    __syncthreads();

    // phase 1: barrier-free
    {
        int w = tid >> 6, l = tid & 63;
        const float* ekp = EkT + (size_t)(w * 32) * 1024 + b * S + l * 4;
        float4 a0 = {0.f, 0.f, 0.f, 0.f};
        float4 a1 = a0, a2 = a0, a3 = a0;
#pragma unroll 8
        for (int pp = 0; pp < 32; ++pp) {
            float4 ek = *(const float4*)(ekp + (size_t)pp * 1024);
            int p = w * 32 + pp;
            float vv = vsm[p];
            float q0 = Eqs[0][p], q1 = Eqs[1][p];
            float q2 = Eqs[2][p], q3 = Eqs[3][p];
            a0.x = fmaf(vv, fast_rcp(fmaf(ek.x, q0, 1.f)), a0.x);
            a0.y = fmaf(vv, fast_rcp(fmaf(ek.y, q0, 1.f)), a0.y);
            a0.z = fmaf(vv, fast_rcp(fmaf(ek.z, q0, 1.f)), a0.z);
            a0.w = fmaf(vv, fast_rcp(fmaf(ek.w, q0, 1.f)), a0.w);
            a1.x = fmaf(vv, fast_rcp(fmaf(ek.x, q1, 1.f)), a1.x);
            a1.y = fmaf(vv, fast_rcp(fmaf(ek.y, q1, 1.f)), a1.y);
            a1.z = fmaf(vv, fast_rcp(fmaf(ek.z, q1, 1.f)), a1.z);
            a1.w = fmaf(vv, fast_rcp(fmaf(ek.w, q1, 1.f)), a1.w);
            a2.x = fmaf(vv, fast_rcp(fmaf(ek.x, q2, 1.f)), a2.x);
            a2.y = fmaf(vv, fast_rcp(fmaf(ek.y, q2, 1.f)), a2.y);
            a2.z = fmaf(vv, fast_rcp(fmaf(ek.z, q2, 1.f)), a2.z);
            a2.w = fmaf(vv, fast_rcp(fmaf(ek.w, q2, 1.f)), a2.w);
            a3.x = fmaf(vv, fast_rcp(fmaf(ek.x, q3, 1.f)), a3.x);
            a3.y = fmaf(vv, fast_rcp(fmaf(ek.y, q3, 1.f)), a3.y);
            a3.z = fmaf(vv, fast_rcp(fmaf(ek.z, q3, 1.f)), a3.z);
            a3.w = fmaf(vv, fast_rcp(fmaf(ek.w, q3, 1.f)), a3.w);
        }
        *(float4*)&part[w][0][l * 4] = a0;
        *(float4*)&part[w][1][l * 4] = a1;
        *(float4*)&part[w][2][l * 4] = a2;
        *(float4*)&part[w][3][l * 4] = a3;
    }
    __syncthreads();

    // phase 2: softmax over keys (threads 0..255 = j); barriers outside ifs
    int j = tid & 255;
    int lane = tid & 63, wid4 = (tid >> 6) & 3;
    float s[4], e[4] = {0.f, 0.f, 0.f, 0.f};
    if (tid < 256) {
        float km = mask[(size_t)b * S + j];
#pragma unroll
        for (int q = 0; q < 4; q++) {
            float sv = ((part[0][q][j] + part[1][q][j]) +
                        (part[2][q][j] + part[3][q][j])) +
                       ((part[4][q][j] + part[5][q][j]) +
                        (part[6][q][j] + part[7][q][j]));
            s[q] = (km > 0.f) ? sv : NEG_INF;
            float mm = s[q];
#pragma unroll
            for (int off = 32; off >= 1; off >>= 1)
                mm = fmaxf(mm, __shfl_xor(mm, off, 64));
            if (lane == 0) redm[q][wid4] = mm;
        }
    }
    __syncthreads();
    if (tid < 256) {
#pragma unroll
        for (int q = 0; q < 4; q++) {
            float mm = fmaxf(fmaxf(redm[q][0], redm[q][1]),
                             fmaxf(redm[q][2], redm[q][3]));
            float ee = fast_exp2((s[q] - mm) * LOG2E);
            e[q] = ee;
            float ss = ee;
#pragma unroll
            for (int off = 32; off >= 1; off >>= 1)
                ss += __shfl_xor(ss, off, 64);
            if (lane == 0) reds[q][wid4] = ss;
        }
    }
    __syncthreads();
    if (tid < 256) {
#pragma unroll
        for (int q = 0; q < 4; q++) {
            float ssum = (reds[q][0] + reds[q][1]) + (reds[q][2] + reds[q][3]);
            float qm = mask[(size_t)b * S + i0 + q];
            float wgt = e[q] * fast_rcp(ssum) * qm;
            wout[((size_t)i0g + q) * S + j] = wgt;
        }
    }
}

// ---------------------------------------------------------------------------
// K3: broadcast attn.  attn[i][d] = sum_j w[i][j] * seq[j][d]
// Block: 8 queries x 256 d (lanes). Weights staged once (4 KB? 8 KB) as
// [j][q] -> b128 broadcasts; seq read coalesced from L2; no k-loop barriers.
// 256 blocks, 256 threads.
// ---------------------------------------------------------------------------
__global__ __launch_bounds__(256)
void attn_kernel(const float* __restrict__ wout, const float* __restrict__ seq,
                 float* __restrict__ attn) {
    __shared__ float wsm[S][8]; // 8 KB
    int b0 = blockIdx.x;
    int bid = (b0 & 7) * 32 + (b0 >> 3); // XCD swizzle (256 = 8*32)
    int ig8 = bid >> 1;  // 0..127 global 8-query group
    int dt = bid & 1;
    int i0g = ig8 * 8;
    int b = i0g >> 8;
    int d0 = dt * 256;
    int tid = threadIdx.x;

    { // stage weights [256 j][8 q], coalesced global reads
        const float* wp = wout + (size_t)i0g * S + tid;
#pragma unroll
        for (int q = 0; q < 8; q++) wsm[tid][q] = wp[(size_t)q * S];
    }
    __syncthreads();

    const float* sp = seq + (size_t)b * S * D + d0 + tid;
    float acc[8] = {0.f, 0.f, 0.f, 0.f, 0.f, 0.f, 0.f, 0.f};
#pragma unroll 4
    for (int j = 0; j < S; ++j) {
        float sv = sp[(size_t)j * D];
        float4 wa = *(const float4*)&wsm[j][0];
        float4 wb = *(const float4*)&wsm[j][4];
        acc[0] = fmaf(wa.x, sv, acc[0]);
        acc[1] = fmaf(wa.y, sv, acc[1]);
        acc[2] = fmaf(wa.z, sv, acc[2]);
        acc[3] = fmaf(wa.w, sv, acc[3]);
        acc[4] = fmaf(wb.x, sv, acc[4]);
        acc[5] = fmaf(wb.y, sv, acc[5]);
        acc[6] = fmaf(wb.z, sv, acc[6]);
        acc[7] = fmaf(wb.w, sv, acc[7]);
    }
    float* op = attn + (size_t)i0g * D + d0 + tid;
#pragma unroll
    for (int q = 0; q < 8; q++) op[(size_t)q * D] = acc[q];
}

// ---------------------------------------------------------------------------
extern "C" void kernel_launch(void* const* d_in, const int* in_sizes, int n_in,
                              void* d_out, int out_size, void* d_ws, size_t ws_size,
                              hipStream_t stream) {
    const float* seq  = (const float*)d_in[0];
    const float* mask = (const float*)d_in[1];
    const float* W1   = (const float*)d_in[2];
    const float* W2   = (const float*)d_in[3];
    const float* v    = (const float*)d_in[4];

    float* attn = (float*)d_out;                 // [B,S,D] = 524288 floats
    float* wout = attn + (size_t)B * S * D;      // [B,S,S]

    // seqT (512x1024 = 524288 floats) reuses the attn region as scratch:
    // written by K0, consumed by K1, overwritten by K3. Deterministic.
    float* seqT = attn;

    float* EqT = (float*)d_ws;                   // [P][B*S] = exp2(C2*pq)^T
    float* EkT = EqT + (size_t)P * B * S;        // [P][B*S] = exp2(C2*pk)^T

    transpose_kernel<<<128, 256, 0, stream>>>(seq, seqT);
    proj_kernel<<<512, 256, 0, stream>>>(seqT, W1, W2, EqT, EkT);
    score_kernel<<<256, 512, 0, stream>>>(EkT, EqT, v, mask, wout);
    attn_kernel<<<256, 256, 0, stream>>>(wout, seq, attn);
}

// Round 11
// 41.815 us; speedup vs baseline: 9.1424x; 1.4089x over previous
//
#include <hip/hip_runtime.h>

// Problem constants (fixed by setup_inputs): B=4, S=256, D=512, P=256
constexpr int B = 4;
constexpr int S = 256;
constexpr int D = 512;
constexpr int P = 256;
constexpr float NEG_INF = -1e9f;
constexpr float LOG2E = 1.4426950408889634f;
constexpr float C2 = 2.885390081777927f; // 2*log2(e): exp2(C2*x) = e^{2x}

__device__ __forceinline__ float fast_exp2(float x) {
#if __has_builtin(__builtin_amdgcn_exp2f)
    return __builtin_amdgcn_exp2f(x);
#else
    return exp2f(x);
#endif
}

__device__ __forceinline__ float fast_rcp(float x) {
#if __has_builtin(__builtin_amdgcn_rcpf)
    return __builtin_amdgcn_rcpf(x);
#else
    return 1.0f / x;
#endif
}

// ---------------------------------------------------------------------------
// proj (R5 version, measured 16.1us — UNCHANGED): 32m x 64n tiles, K-tile 64,
// 256 blocks, 256 thr, 2m x 4n thread tile, reg prefetch, exp2 epilogue.
//   bid < 128 : Eq[b*S+i][p]   bid >= 128 : EkT[b][p][j]
// ---------------------------------------------------------------------------
__global__ __launch_bounds__(256)
void proj_kernel(const float* __restrict__ seq,
                 const float* __restrict__ W1, const float* __restrict__ W2,
                 float* __restrict__ Eq, float* __restrict__ EkT) {
    __shared__ float As[64][34]; // [k][m]
    __shared__ float Ws[64][68]; // [k][n]

    int bid0 = blockIdx.x;
    int bid = (bid0 & 7) * 32 + (bid0 >> 3); // XCD swizzle (256 = 8*32)

    const float* A;
    const float* Bp;
    float* out;
    if (bid < 128) { // Eq
        int mt = bid >> 2, nt = bid & 3;
        A = seq + (size_t)mt * 32 * D;
        Bp = W2 + (size_t)nt * 64 * D;
        out = Eq + (size_t)mt * 32 * 256 + nt * 64;
    } else {         // EkT
        int r = bid - 128;
        int b = r >> 5, t = r & 31;
        int mt = t >> 2, nt = t & 3;
        A = W1 + (size_t)mt * 32 * D;
        Bp = seq + ((size_t)b * S + nt * 64) * D;
        out = EkT + (size_t)b * P * S + (size_t)mt * 32 * 256 + nt * 64;
    }

    int tid = threadIdx.x;
    int tx = tid & 15, ty = tid >> 4;
    int ar = tid >> 3, acg = tid & 7;
    int br = tid >> 2, bcg = tid & 3;
    const float* aptr = A + (size_t)ar * D + acg * 8;
    const float* bptr = Bp + (size_t)br * D + bcg * 16;

    float4 a0, a1, w0, w1, w2, w3;
    a0 = *(const float4*)(aptr);      a1 = *(const float4*)(aptr + 4);
    w0 = *(const float4*)(bptr);      w1 = *(const float4*)(bptr + 4);
    w2 = *(const float4*)(bptr + 8);  w3 = *(const float4*)(bptr + 12);

    float c0[4] = {0.f, 0.f, 0.f, 0.f};
    float c1[4] = {0.f, 0.f, 0.f, 0.f};

    for (int kt = 0; kt < 8; kt++) {
        int ka = acg * 8;
        As[ka + 0][ar] = a0.x; As[ka + 1][ar] = a0.y;
        As[ka + 2][ar] = a0.z; As[ka + 3][ar] = a0.w;
        As[ka + 4][ar] = a1.x; As[ka + 5][ar] = a1.y;
        As[ka + 6][ar] = a1.z; As[ka + 7][ar] = a1.w;
        int kb = bcg * 16;
        Ws[kb + 0][br] = w0.x;  Ws[kb + 1][br] = w0.y;
        Ws[kb + 2][br] = w0.z;  Ws[kb + 3][br] = w0.w;
        Ws[kb + 4][br] = w1.x;  Ws[kb + 5][br] = w1.y;
        Ws[kb + 6][br] = w1.z;  Ws[kb + 7][br] = w1.w;
        Ws[kb + 8][br] = w2.x;  Ws[kb + 9][br] = w2.y;
        Ws[kb + 10][br] = w2.z; Ws[kb + 11][br] = w2.w;
        Ws[kb + 12][br] = w3.x; Ws[kb + 13][br] = w3.y;
        Ws[kb + 14][br] = w3.z; Ws[kb + 15][br] = w3.w;
        __syncthreads();
        if (kt < 7) {
            const float* ap = aptr + (kt + 1) * 64;
            const float* bp = bptr + (kt + 1) * 64;
            a0 = *(const float4*)(ap);     a1 = *(const float4*)(ap + 4);
            w0 = *(const float4*)(bp);     w1 = *(const float4*)(bp + 4);
            w2 = *(const float4*)(bp + 8); w3 = *(const float4*)(bp + 12);
        }
#pragma unroll 8
        for (int k = 0; k < 64; k++) {
            float2 av = *(const float2*)&As[k][ty * 2];
            float4 wv = *(const float4*)&Ws[k][tx * 4];
            c0[0] = fmaf(av.x, wv.x, c0[0]);
            c0[1] = fmaf(av.x, wv.y, c0[1]);
            c0[2] = fmaf(av.x, wv.z, c0[2]);
            c0[3] = fmaf(av.x, wv.w, c0[3]);
            c1[0] = fmaf(av.y, wv.x, c1[0]);
            c1[1] = fmaf(av.y, wv.y, c1[1]);
            c1[2] = fmaf(av.y, wv.z, c1[2]);
            c1[3] = fmaf(av.y, wv.w, c1[3]);
        }
        __syncthreads();
    }
    float4 o0 = {fast_exp2(c0[0] * C2), fast_exp2(c0[1] * C2),
                 fast_exp2(c0[2] * C2), fast_exp2(c0[3] * C2)};
    float4 o1 = {fast_exp2(c1[0] * C2), fast_exp2(c1[1] * C2),
                 fast_exp2(c1[2] * C2), fast_exp2(c1[3] * C2)};
    *(float4*)&out[(size_t)(ty * 2 + 0) * 256 + tx * 4] = o0;
    *(float4*)&out[(size_t)(ty * 2 + 1) * 256 + tx * 4] = o1;
}

// ---------------------------------------------------------------------------
// score v9: block = (b, 2 queries), 512 threads, 512 blocks (16 waves/CU).
//  score(i,j) = const + sum_p (-2 v[p]) * rcp(Eq[i,p]*EkT[b][p][j] + 1)
// Phase 1 (barrier-free): thread = (j, p-half h). Per p-step: one b32
// j-coalesced EkT load + wave-uniform Eq/v broadcasts + 2 rcp chains.
// Phase 2: softmax (threads 0..255 = j) -> wout (query-mask applied).
// ---------------------------------------------------------------------------
__global__ __launch_bounds__(512)
void score_kernel(const float* __restrict__ EkT, const float* __restrict__ Eq,
                  const float* __restrict__ v, const float* __restrict__ mask,
                  float* __restrict__ wout) {
    __shared__ float Eqs[2][P];        // 2 KB
    __shared__ float vsm[P];           // 1 KB (-2v)
    __shared__ float part[2][2][S];    // 4 KB [h][q][j]
    __shared__ float redm[2][4], reds[2][4];

    int b0 = blockIdx.x;
    int bid = (b0 & 7) * 64 + (b0 >> 3); // XCD swizzle (512 = 8*64)
    int b = bid >> 7;
    int i0 = (bid & 127) * 2;
    int tid = threadIdx.x;
    int j = tid & 255, h = tid >> 8;

    // stage 2 Eq rows (512 contiguous floats; one per thread) and v' = -2v
    ((float*)Eqs)[tid] = Eq[((size_t)b * S + i0) * P + tid];
    if (tid < 256) vsm[tid] = -2.f * v[tid];
    __syncthreads();

    // phase 1: barrier-free; 128 p-steps for this thread's half
    {
        const float* ekp = EkT + ((size_t)b * P + h * 128) * S + j;
        float a0 = 0.f, a1 = 0.f;
        int pb = h * 128;
#pragma unroll 8
        for (int pp = 0; pp < 128; ++pp) {
            float ek = ekp[(size_t)pp * S];
            int p = pb + pp;
            float vv = vsm[p];
            float e0 = Eqs[0][p], e1 = Eqs[1][p];
            a0 = fmaf(vv, fast_rcp(fmaf(ek, e0, 1.f)), a0);
            a1 = fmaf(vv, fast_rcp(fmaf(ek, e1, 1.f)), a1);
        }
        part[h][0][j] = a0;
        part[h][1][j] = a1;
    }
    __syncthreads();

    // phase 2: softmax over keys (threads 0..255 = j)
    int lane = tid & 63, wid = tid >> 6; // wid 0..3 for tid<256
    float s0 = 0.f, s1 = 0.f, e0 = 0.f, e1 = 0.f;
    if (tid < 256) {
        float km = mask[(size_t)b * S + j];
        s0 = part[0][0][j] + part[1][0][j];
        s1 = part[0][1][j] + part[1][1][j];
        if (!(km > 0.f)) { s0 = NEG_INF; s1 = NEG_INF; }
        float m0 = s0, m1 = s1;
#pragma unroll
        for (int off = 32; off >= 1; off >>= 1) {
            m0 = fmaxf(m0, __shfl_xor(m0, off, 64));
            m1 = fmaxf(m1, __shfl_xor(m1, off, 64));
        }
        if (lane == 0) { redm[0][wid] = m0; redm[1][wid] = m1; }
    }
    __syncthreads();
    if (tid < 256) {
        float m0 = fmaxf(fmaxf(redm[0][0], redm[0][1]),
                         fmaxf(redm[0][2], redm[0][3]));
        float m1 = fmaxf(fmaxf(redm[1][0], redm[1][1]),
                         fmaxf(redm[1][2], redm[1][3]));
        e0 = fast_exp2((s0 - m0) * LOG2E);
        e1 = fast_exp2((s1 - m1) * LOG2E);
        float t0 = e0, t1 = e1;
#pragma unroll
        for (int off = 32; off >= 1; off >>= 1) {
            t0 += __shfl_xor(t0, off, 64);
            t1 += __shfl_xor(t1, off, 64);
        }
        if (lane == 0) { reds[0][wid] = t0; reds[1][wid] = t1; }
    }
    __syncthreads();
    if (tid < 256) {
        float sum0 = (reds[0][0] + reds[0][1]) + (reds[0][2] + reds[0][3]);
        float sum1 = (reds[1][0] + reds[1][1]) + (reds[1][2] + reds[1][3]);
        float qm0 = mask[(size_t)b * S + i0];
        float qm1 = mask[(size_t)b * S + i0 + 1];
        float w0 = e0 * fast_rcp(sum0) * qm0;
        float w1 = e1 * fast_rcp(sum1) * qm1;
        wout[((size_t)b * S + i0 + 0) * S + j] = w0;
        wout[((size_t)b * S + i0 + 1) * S + j] = w1;
    }
}

// ---------------------------------------------------------------------------
// attn broadcast (R10-K3, numerically validated): attn[i][d] = sum_j w[i][j]
// * seq[j][d]. Block = 8 queries x 256 d-lanes; w staged once as [j][q] ->
// b128 broadcasts; seq L2-coalesced b32; no k-loop barriers; unroll 8.
// 256 blocks, 256 threads.
// ---------------------------------------------------------------------------
__global__ __launch_bounds__(256)
void attn_kernel(const float* __restrict__ wout, const float* __restrict__ seq,
                 float* __restrict__ attn) {
    __shared__ float wsm[S][8]; // 8 KB
    int b0 = blockIdx.x;
    int bid = (b0 & 7) * 32 + (b0 >> 3); // XCD swizzle (256 = 8*32)
    int ig8 = bid >> 1;  // 0..127 global 8-query group
    int dt = bid & 1;
    int i0g = ig8 * 8;
    int b = i0g >> 8;
    int d0 = dt * 256;
    int tid = threadIdx.x;

    { // stage weights [256 j][8 q], coalesced global reads
        const float* wp = wout + (size_t)i0g * S + tid;
#pragma unroll
        for (int q = 0; q < 8; q++) wsm[tid][q] = wp[(size_t)q * S];
    }
    __syncthreads();

    const float* sp = seq + (size_t)b * S * D + d0 + tid;
    float acc[8] = {0.f, 0.f, 0.f, 0.f, 0.f, 0.f, 0.f, 0.f};
#pragma unroll 8
    for (int j = 0; j < S; ++j) {
        float sv = sp[(size_t)j * D];
        float4 wa = *(const float4*)&wsm[j][0];
        float4 wb = *(const float4*)&wsm[j][4];
        acc[0] = fmaf(wa.x, sv, acc[0]);
        acc[1] = fmaf(wa.y, sv, acc[1]);
        acc[2] = fmaf(wa.z, sv, acc[2]);
        acc[3] = fmaf(wa.w, sv, acc[3]);
        acc[4] = fmaf(wb.x, sv, acc[4]);
        acc[5] = fmaf(wb.y, sv, acc[5]);
        acc[6] = fmaf(wb.z, sv, acc[6]);
        acc[7] = fmaf(wb.w, sv, acc[7]);
    }
    float* op = attn + (size_t)i0g * D + d0 + tid;
#pragma unroll
    for (int q = 0; q < 8; q++) op[(size_t)q * D] = acc[q];
}

// ---------------------------------------------------------------------------
extern "C" void kernel_launch(void* const* d_in, const int* in_sizes, int n_in,
                              void* d_out, int out_size, void* d_ws, size_t ws_size,
                              hipStream_t stream) {
    const float* seq  = (const float*)d_in[0];
    const float* mask = (const float*)d_in[1];
    const float* W1   = (const float*)d_in[2];
    const float* W2   = (const float*)d_in[3];
    const float* v    = (const float*)d_in[4];

    float* attn = (float*)d_out;                 // [B,S,D]
    float* wout = attn + (size_t)B * S * D;      // [B,S,S]

    float* Eq  = (float*)d_ws;                   // [B*S, P]  = exp2(C2*pq)
    float* EkT = Eq + (size_t)B * S * P;         // [B, P, S] = exp2(C2*pk)^T

    proj_kernel<<<256, 256, 0, stream>>>(seq, W1, W2, Eq, EkT);
    score_kernel<<<512, 512, 0, stream>>>(EkT, Eq, v, mask, wout);
    attn_kernel<<<256, 256, 0, stream>>>(wout, seq, attn);
}